// Round 8
// baseline (530.134 us; speedup 1.0000x reference)
//
#include <hip/hip_runtime.h>

#define HD 64
#define VOCAB 64
#define BATCH 256
#define SEQLEN 2048
#define NSTEPS ((SEQLEN - 2) / 2)   // 1023
#define LRc 0.05f

// ---------------- Kernel 1: build the 64x64 encoder table ----------------
__global__ __launch_bounds__(64, 1) void enc_build(
    const float* __restrict__ embed, const float* __restrict__ ffw1,
    const float* __restrict__ ffb1, const float* __restrict__ ffw2,
    const float* __restrict__ ffb2, const float* __restrict__ ln_g,
    const float* __restrict__ ln_b, float* __restrict__ enc) {
  const int v = blockIdx.x, j = threadIdx.x;
  __shared__ float e_s[HD];
  __shared__ float hid_s[2 * HD];
  float e = embed[v * HD + j];
  e_s[j] = e;
  __syncthreads();
  float ha = ffb1[j], hb = ffb1[HD + j];
  #pragma unroll 8
  for (int h = 0; h < HD; ++h) {
    float eh = e_s[h];
    ha = fmaf(ffw1[j * HD + h], eh, ha);
    hb = fmaf(ffw1[(HD + j) * HD + h], eh, hb);
  }
  hid_s[j] = fmaxf(ha, 0.f);
  hid_s[HD + j] = fmaxf(hb, 0.f);
  __syncthreads();
  float ff = ffb2[j];
  #pragma unroll 8
  for (int h2 = 0; h2 < 2 * HD; ++h2) ff = fmaf(ffw2[j * 2 * HD + h2], hid_s[h2], ff);
  float x = e + ff;
  float mu = x;
  #pragma unroll
  for (int m = 1; m < 64; m <<= 1) mu += __shfl_xor(mu, m, 64);
  mu *= (1.f / 64.f);
  float xc = x - mu;
  float var = xc * xc;
  #pragma unroll
  for (int m = 1; m < 64; m <<= 1) var += __shfl_xor(var, m, 64);
  var *= (1.f / 64.f);
  enc[v * HD + j] = xc / sqrtf(var + 1e-5f) * ln_g[j] + ln_b[j];
}

// ---------------- Kernel 1b: Gram matrix G[u][v] = enc_u . enc_v ----------------
__global__ __launch_bounds__(64, 1) void gram_build(
    const float* __restrict__ enc, float* __restrict__ G) {
  __shared__ float es[VOCAB * HD];
  const int u = blockIdx.x, v = threadIdx.x;
  #pragma unroll
  for (int q = 0; q < 16; ++q)
    ((float4*)es)[v + 64 * q] = ((const float4*)enc)[v + 64 * q];
  __syncthreads();
  const float* a = &es[u * HD];
  const float* bb = &es[v * HD];
  float s0 = 0.f, s1 = 0.f, s2 = 0.f, s3 = 0.f;
  #pragma unroll
  for (int j = 0; j < HD; j += 4) {
    s0 = fmaf(a[j + 0], bb[j + 0], s0);
    s1 = fmaf(a[j + 1], bb[j + 1], s1);
    s2 = fmaf(a[j + 2], bb[j + 2], s2);
    s3 = fmaf(a[j + 3], bb[j + 3], s3);
  }
  G[u * VOCAB + v] = (s0 + s1) + (s2 + s3);
}

// ---------------- Kernel 2: the sequential TTT scan ----------------
// One wave per chain, state in VGPRs. lane l = 32*half + i:
//   W1[c]  = w1[i][32*half + c]
//   W2R[c] = w2[l][c]
//   W2T[r] = w2[32*half + r][i]
// Recurrence hoist: pre_{t+1} = (W1_t @ k_{t+1}) + dh_t * (k_t . k_{t+1}) + b1_{t+1}
// POF = W1_t @ k_{t+1} computed off-path during step t; k_t.k_{t+1} = G[tok_t][tok_{t+1}].
__device__ __forceinline__ void ttt_step(
    int l, int half,
    const float* __restrict__ enc_s, const float* __restrict__ G_s,
    const int* __restrict__ seq_s, float* __restrict__ sd_s,
    float (&W1)[32], float (&W2R)[32], float (&W2T)[32],
    float& b1r, float& b2r,
    float (&KC)[32], float& vvC, float (&KN)[32], float& vvN,
    float& POF, float& KKF, float& dhp,
    int2& tk, int2& tk1, int pidx) {
  // ---- pre from carried rank-1 correction (critical path: add+fma+max) ----
  float pre = fmaf(dhp, KKF, POF + b1r);
  float h = fmaxf(pre, 0.f);

  // ---- prefetch next tokens' K/vv and Gram entry (off-path) ----
  const float* krn = &enc_s[tk1.x * HD + half * 32];
  #pragma unroll
  for (int q = 0; q < 8; ++q) *(float4*)&KN[4 * q] = *(const float4*)&krn[4 * q];
  vvN = enc_s[tk1.y * HD + l];
  float KKFn = G_s[tk.x * VOCAB + tk1.x];   // k_t . k_{t+1}, broadcast read
  int2 tk2 = *(const int2*)&seq_s[pidx];

  // ---- broadcast h[0..31] via v_readlane (SGPRs) ----
  float sh[32];
  #pragma unroll
  for (int c = 0; c < 32; ++c)
    sh[c] = __int_as_float(__builtin_amdgcn_readlane(__float_as_int(h), c));

  // ---- pred[l] = w2[l,:] @ h + b2[l] ----
  float q0 = b2r, q1 = 0.f, q2 = 0.f, q3 = 0.f;
  #pragma unroll
  for (int c = 0; c < 32; c += 4) {
    q0 = fmaf(W2R[c + 0], sh[c + 0], q0);
    q1 = fmaf(W2R[c + 1], sh[c + 1], q1);
    q2 = fmaf(W2R[c + 2], sh[c + 2], q2);
    q3 = fmaf(W2R[c + 3], sh[c + 3], q3);
  }
  float pred = (q0 + q1) + (q2 + q3);
  float sR = (vvC - pred) * (2.f * LRc / (float)HD);
  sd_s[l] = sR;  // scaled-d broadcast; latency hidden by the fill work below

  // ---- fill work (independent of SD): POF for next step (W1 BEFORE update), W2R update ----
  float p0 = 0.f, p1 = 0.f, p2 = 0.f, p3 = 0.f;
  #pragma unroll
  for (int c = 0; c < 32; c += 4) {
    p0 = fmaf(W1[c + 0], KN[c + 0], p0);
    p1 = fmaf(W1[c + 1], KN[c + 1], p1);
    p2 = fmaf(W1[c + 2], KN[c + 2], p2);
    p3 = fmaf(W1[c + 3], KN[c + 3], p3);
  }
  float pp = (p0 + p1) + (p2 + p3);
  float POFn = pp + __shfl_xor(pp, 32, 64);
  #pragma unroll
  for (int c = 0; c < 32; ++c) W2R[c] = fmaf(sR, sh[c], W2R[c]);
  b2r += sR;

  // ---- read scaled-d for this half ----
  float SD[32];
  const float* drp = &sd_s[half * 32];
  #pragma unroll
  for (int q = 0; q < 8; ++q) *(float4*)&SD[4 * q] = *(const float4*)&drp[4 * q];

  // ---- dh' = -LR * (w2^T @ d)[i], masked by relu ----
  float g0 = 0.f, g1 = 0.f, g2 = 0.f, g3 = 0.f;
  #pragma unroll
  for (int r = 0; r < 32; r += 4) {
    g0 = fmaf(W2T[r + 0], SD[r + 0], g0);
    g1 = fmaf(W2T[r + 1], SD[r + 1], g1);
    g2 = fmaf(W2T[r + 2], SD[r + 2], g2);
    g3 = fmaf(W2T[r + 3], SD[r + 3], g3);
  }
  float gpart = (g0 + g1) + (g2 + g3);
  float dh = gpart + __shfl_xor(gpart, 32, 64);
  dh = (pre > 0.f) ? dh : 0.f;

  // ---- remaining updates ----
  #pragma unroll
  for (int r = 0; r < 32; ++r) W2T[r] = fmaf(SD[r], h, W2T[r]);
  #pragma unroll
  for (int c = 0; c < 32; ++c) W1[c] = fmaf(dh, KC[c], W1[c]);
  b1r += dh;

  // ---- carry ----
  POF = POFn;
  KKF = KKFn;
  dhp = dh;
  tk = tk1;
  tk1 = tk2;
}

__global__ __launch_bounds__(64, 1) void ttt_run(
    const int* __restrict__ seq, const float* __restrict__ enc,
    const float* __restrict__ Gg,
    const float* __restrict__ w1g, const float* __restrict__ b1g,
    const float* __restrict__ w2g, const float* __restrict__ b2g,
    const float* __restrict__ woutg, const float* __restrict__ boutg,
    float* __restrict__ out) {
  __shared__ float enc_s[VOCAB * HD];     // 16 KB
  __shared__ float G_s[VOCAB * VOCAB];    // 16 KB
  __shared__ int   seq_s[SEQLEN];         // 8 KB
  __shared__ float sd_s[64];
  __shared__ float ctx_s[64];
  const int b = blockIdx.x, l = threadIdx.x;
  const int i = l & 31, half = l >> 5;

  #pragma unroll
  for (int q = 0; q < 16; ++q)
    ((float4*)enc_s)[l + 64 * q] = ((const float4*)enc)[l + 64 * q];
  #pragma unroll
  for (int q = 0; q < 16; ++q)
    ((float4*)G_s)[l + 64 * q] = ((const float4*)Gg)[l + 64 * q];
  const int4* seqg = (const int4*)(seq + b * SEQLEN);
  #pragma unroll
  for (int q = 0; q < 8; ++q)
    ((int4*)seq_s)[l + 64 * q] = seqg[l + 64 * q];

  float W1[32], W2R[32], W2T[32];
  #pragma unroll
  for (int q = 0; q < 8; ++q)
    *(float4*)&W1[4 * q] = *(const float4*)&w1g[i * 64 + half * 32 + 4 * q];
  #pragma unroll
  for (int q = 0; q < 8; ++q)
    *(float4*)&W2R[4 * q] = *(const float4*)&w2g[l * 32 + 4 * q];
  #pragma unroll
  for (int r = 0; r < 32; ++r) W2T[r] = w2g[(half * 32 + r) * 32 + i];
  float b1r = b1g[i];
  float b2r = b2g[l];
  __syncthreads();

  int2 tk  = *(const int2*)&seq_s[0];
  int2 tk1 = *(const int2*)&seq_s[2];
  float KA[32], KB[32], vvA, vvB;
  {
    const float* kr = &enc_s[tk.x * HD + half * 32];
    #pragma unroll
    for (int q = 0; q < 8; ++q) *(float4*)&KA[4 * q] = *(const float4*)&kr[4 * q];
    vvA = enc_s[tk.y * HD + l];
  }
  // POF init: full dot W1 @ k_0 (first step: dhp=0, KKF=0)
  float POF, KKF = 0.f, dhp = 0.f;
  {
    float p0 = 0.f, p1 = 0.f, p2 = 0.f, p3 = 0.f;
    #pragma unroll
    for (int c = 0; c < 32; c += 4) {
      p0 = fmaf(W1[c + 0], KA[c + 0], p0);
      p1 = fmaf(W1[c + 1], KA[c + 1], p1);
      p2 = fmaf(W1[c + 2], KA[c + 2], p2);
      p3 = fmaf(W1[c + 3], KA[c + 3], p3);
    }
    float pp = (p0 + p1) + (p2 + p3);
    POF = pp + __shfl_xor(pp, 32, 64);
  }

  // 511 unrolled pairs (1022 steps) + 1 final step = 1023
  for (int s = 0; s < NSTEPS - 1; s += 2) {
    ttt_step(l, half, enc_s, G_s, seq_s, sd_s, W1, W2R, W2T, b1r, b2r,
             KA, vvA, KB, vvB, POF, KKF, dhp, tk, tk1, 2 * s + 4);
    ttt_step(l, half, enc_s, G_s, seq_s, sd_s, W1, W2R, W2T, b1r, b2r,
             KB, vvB, KA, vvA, POF, KKF, dhp, tk, tk1, 2 * s + 6);
  }
  ttt_step(l, half, enc_s, G_s, seq_s, sd_s, W1, W2R, W2T, b1r, b2r,
           KA, vvA, KB, vvB, POF, KKF, dhp, tk, tk1, 2046 /*result unused*/);

  // ---- tail: ctx = w2f @ relu(w1f @ enc[seq[L-1]] + b1f) + b2f ----
  {
    int tok = seq_s[SEQLEN - 1];
    float K[32];
    const float* kr = &enc_s[tok * HD + half * 32];
    #pragma unroll
    for (int q = 0; q < 8; ++q) *(float4*)&K[4 * q] = *(const float4*)&kr[4 * q];
    float a0 = 0.f, a1 = 0.f, a2 = 0.f, a3 = 0.f;
    #pragma unroll
    for (int c = 0; c < 32; c += 4) {
      a0 = fmaf(W1[c + 0], K[c + 0], a0);
      a1 = fmaf(W1[c + 1], K[c + 1], a1);
      a2 = fmaf(W1[c + 2], K[c + 2], a2);
      a3 = fmaf(W1[c + 3], K[c + 3], a3);
    }
    float part = (a0 + a1) + (a2 + a3);
    float pre = part + __shfl_xor(part, 32, 64) + b1r;
    float h = fmaxf(pre, 0.f);
    float sh[32];
    #pragma unroll
    for (int c = 0; c < 32; ++c)
      sh[c] = __int_as_float(__builtin_amdgcn_readlane(__float_as_int(h), c));
    float q0 = b2r, q1 = 0.f, q2 = 0.f, q3 = 0.f;
    #pragma unroll
    for (int c = 0; c < 32; c += 4) {
      q0 = fmaf(W2R[c + 0], sh[c + 0], q0);
      q1 = fmaf(W2R[c + 1], sh[c + 1], q1);
      q2 = fmaf(W2R[c + 2], sh[c + 2], q2);
      q3 = fmaf(W2R[c + 3], sh[c + 3], q3);
    }
    ctx_s[l] = (q0 + q1) + (q2 + q3);
    __syncthreads();
    float acc = boutg[l];
    #pragma unroll 8
    for (int jj = 0; jj < 64; ++jj) acc = fmaf(woutg[l * 64 + jj], ctx_s[jj], acc);
    out[b * 64 + l] = acc;
  }
}

extern "C" void kernel_launch(void* const* d_in, const int* in_sizes, int n_in,
                              void* d_out, int out_size, void* d_ws, size_t ws_size,
                              hipStream_t stream) {
  const int*   seq   = (const int*)d_in[0];
  const float* embed = (const float*)d_in[1];
  const float* ffw1  = (const float*)d_in[2];
  const float* ffb1  = (const float*)d_in[3];
  const float* ffw2  = (const float*)d_in[4];
  const float* ffb2  = (const float*)d_in[5];
  const float* ln_g  = (const float*)d_in[6];
  const float* ln_b  = (const float*)d_in[7];
  const float* w1    = (const float*)d_in[8];
  const float* b1    = (const float*)d_in[9];
  const float* w2    = (const float*)d_in[10];
  const float* b2    = (const float*)d_in[11];
  const float* wout  = (const float*)d_in[12];
  const float* bout  = (const float*)d_in[13];
  float* enc = (float*)d_ws;           // 4096 floats
  float* G   = (float*)d_ws + 4096;    // 4096 floats

  enc_build<<<VOCAB, 64, 0, stream>>>(embed, ffw1, ffb1, ffw2, ffb2, ln_g, ln_b, enc);
  gram_build<<<VOCAB, 64, 0, stream>>>(enc, G);
  ttt_run<<<BATCH, 64, 0, stream>>>(seq, enc, G, w1, b1, w2, b2, wout, bout, (float*)d_out);
}

// Round 10
// 397.850 us; speedup vs baseline: 1.3325x; 1.3325x over previous
//
#include <hip/hip_runtime.h>

#define HD 64
#define VOCAB 64
#define BATCH 256
#define SEQLEN 2048
#define NSTEPS ((SEQLEN - 2) / 2)   // 1023
#define LRc 0.05f

typedef __attribute__((ext_vector_type(2))) float f2;

// ---------------- Kernel 1: build the 64x64 encoder table ----------------
__global__ __launch_bounds__(64, 1) void enc_build(
    const float* __restrict__ embed, const float* __restrict__ ffw1,
    const float* __restrict__ ffb1, const float* __restrict__ ffw2,
    const float* __restrict__ ffb2, const float* __restrict__ ln_g,
    const float* __restrict__ ln_b, float* __restrict__ enc) {
  const int v = blockIdx.x, j = threadIdx.x;
  __shared__ float e_s[HD];
  __shared__ float hid_s[2 * HD];
  float e = embed[v * HD + j];
  e_s[j] = e;
  __syncthreads();
  float ha = ffb1[j], hb = ffb1[HD + j];
  #pragma unroll 8
  for (int h = 0; h < HD; ++h) {
    float eh = e_s[h];
    ha = fmaf(ffw1[j * HD + h], eh, ha);
    hb = fmaf(ffw1[(HD + j) * HD + h], eh, hb);
  }
  hid_s[j] = fmaxf(ha, 0.f);
  hid_s[HD + j] = fmaxf(hb, 0.f);
  __syncthreads();
  float ff = ffb2[j];
  #pragma unroll 8
  for (int h2 = 0; h2 < 2 * HD; ++h2) ff = fmaf(ffw2[j * 2 * HD + h2], hid_s[h2], ff);
  float x = e + ff;
  float mu = x;
  #pragma unroll
  for (int m = 1; m < 64; m <<= 1) mu += __shfl_xor(mu, m, 64);
  mu *= (1.f / 64.f);
  float xc = x - mu;
  float var = xc * xc;
  #pragma unroll
  for (int m = 1; m < 64; m <<= 1) var += __shfl_xor(var, m, 64);
  var *= (1.f / 64.f);
  enc[v * HD + j] = xc / sqrtf(var + 1e-5f) * ln_g[j] + ln_b[j];
}

// ---------------- Kernel 1b: Gram matrix G[u][v] = enc_u . enc_v ----------------
__global__ __launch_bounds__(64, 1) void gram_build(
    const float* __restrict__ enc, float* __restrict__ G) {
  __shared__ float es[VOCAB * HD];
  const int u = blockIdx.x, v = threadIdx.x;
  #pragma unroll
  for (int q = 0; q < 16; ++q)
    ((float4*)es)[v + 64 * q] = ((const float4*)enc)[v + 64 * q];
  __syncthreads();
  const float* a = &es[u * HD];
  const float* bb = &es[v * HD];
  float s0 = 0.f, s1 = 0.f, s2 = 0.f, s3 = 0.f;
  #pragma unroll
  for (int j = 0; j < HD; j += 4) {
    s0 = fmaf(a[j + 0], bb[j + 0], s0);
    s1 = fmaf(a[j + 1], bb[j + 1], s1);
    s2 = fmaf(a[j + 2], bb[j + 2], s2);
    s3 = fmaf(a[j + 3], bb[j + 3], s3);
  }
  G[u * VOCAB + v] = (s0 + s1) + (s2 + s3);
}

// ---------------- Kernel 2: the sequential TTT scan ----------------
// One wave per chain, state in VGPRs. lane l = 32*half + i:
//   W1[c]  = w1[i][32*half + 2c..2c+1]   (f2 pairs)
//   W2R[c] = w2[l][c]                     (scalar, updated with SGPR sh)
//   W2T[r] = w2[32*half + 2r..2r+1][i]    (f2 pairs)
// Carry: pre_{t+1} = (W1_t @ k_{t+1}) + dh_t * G[tok_t][tok_{t+1}] + b1.
// POF dot placed at END of step so KN (loaded this step) has ~150 insts of slack.
// pk-f32: POF/dh dots + W2T/W1 updates as float2 elementwise fma (v_pk_fma_f32).
__device__ __forceinline__ void ttt_step(
    int l, int half,
    const float* __restrict__ enc_s, const float* __restrict__ G_s,
    const int* __restrict__ seq_s, float* __restrict__ sd_s,
    f2 (&W1)[16], float (&W2R)[32], f2 (&W2T)[16],
    float& b1r, float& b2r,
    f2 (&KC)[16], float& vvC, f2 (&KN)[16], float& vvN,
    float& POF, float& KKF, float& dhp,
    int2& tk, int2& tk1, int pidx) {
  // ---- pre from carried rank-1 correction (critical path: add+fma+max) ----
  float pre = fmaf(dhp, KKF, POF + b1r);
  float h = fmaxf(pre, 0.f);

  // ---- prefetch next tokens' K/vv/Gram/seq (consumed late this step / next step) ----
  const float* krn = &enc_s[tk1.x * HD + half * 32];
  #pragma unroll
  for (int q = 0; q < 8; ++q) {
    float4 t = *(const float4*)&krn[4 * q];
    KN[2 * q]     = f2{t.x, t.y};
    KN[2 * q + 1] = f2{t.z, t.w};
  }
  vvN = enc_s[tk1.y * HD + l];
  float KKFn = G_s[tk.x * VOCAB + tk1.x];
  int2 tk2 = *(const int2*)&seq_s[pidx];

  // ---- broadcast h[0..31] via v_readlane (SGPRs) ----
  float sh[32];
  #pragma unroll
  for (int c = 0; c < 32; ++c)
    sh[c] = __int_as_float(__builtin_amdgcn_readlane(__float_as_int(h), c));

  // ---- pred[l] = w2[l,:] @ h + b2[l]  (scalar fma, SGPR src is free) ----
  float q0 = b2r, q1 = 0.f, q2 = 0.f, q3 = 0.f;
  #pragma unroll
  for (int c = 0; c < 32; c += 4) {
    q0 = fmaf(W2R[c + 0], sh[c + 0], q0);
    q1 = fmaf(W2R[c + 1], sh[c + 1], q1);
    q2 = fmaf(W2R[c + 2], sh[c + 2], q2);
    q3 = fmaf(W2R[c + 3], sh[c + 3], q3);
  }
  float pred = (q0 + q1) + (q2 + q3);
  float sR = (vvC - pred) * (2.f * LRc / (float)HD);
  sd_s[l] = sR;  // scaled-d broadcast; W2R update below fills the round-trip

  // ---- W2R update (fill, independent of SD) ----
  #pragma unroll
  for (int c = 0; c < 32; ++c) W2R[c] = fmaf(sR, sh[c], W2R[c]);
  b2r += sR;

  // ---- read scaled-d for this half ----
  f2 SD[16];
  const float* drp = &sd_s[half * 32];
  #pragma unroll
  for (int q = 0; q < 8; ++q) {
    float4 t = *(const float4*)&drp[4 * q];
    SD[2 * q]     = f2{t.x, t.y};
    SD[2 * q + 1] = f2{t.z, t.w};
  }

  // ---- dh' = -LR * (w2^T @ d)[i], masked by relu (pk) ----
  f2 g0 = {0.f, 0.f}, g1 = {0.f, 0.f};
  #pragma unroll
  for (int r = 0; r < 16; r += 2) {
    g0 = __builtin_elementwise_fma(W2T[r + 0], SD[r + 0], g0);
    g1 = __builtin_elementwise_fma(W2T[r + 1], SD[r + 1], g1);
  }
  f2 gs = g0 + g1;
  float gpart = gs.x + gs.y;
  float dh = gpart + __shfl_xor(gpart, 32, 64);
  dh = (pre > 0.f) ? dh : 0.f;

  // ---- W2T update (pk; per-element fma keeps bitwise consistency with W2R) ----
  f2 h2 = {h, h};
  #pragma unroll
  for (int r = 0; r < 16; ++r) W2T[r] = __builtin_elementwise_fma(SD[r], h2, W2T[r]);

  // ---- POF for next step: W1 (PRE-update) @ k_{t+1}  (pk; KN latency long hidden) ----
  f2 p0 = {0.f, 0.f}, p1 = {0.f, 0.f};
  #pragma unroll
  for (int c = 0; c < 16; c += 2) {
    p0 = __builtin_elementwise_fma(W1[c + 0], KN[c + 0], p0);
    p1 = __builtin_elementwise_fma(W1[c + 1], KN[c + 1], p1);
  }
  f2 ps = p0 + p1;
  float pp = ps.x + ps.y;
  float POFn = pp + __shfl_xor(pp, 32, 64);

  // ---- W1 update (pk) ----
  f2 dh2 = {dh, dh};
  #pragma unroll
  for (int c = 0; c < 16; ++c) W1[c] = __builtin_elementwise_fma(dh2, KC[c], W1[c]);
  b1r += dh;

  // ---- carry ----
  POF = POFn;
  KKF = KKFn;
  dhp = dh;
  tk = tk1;
  tk1 = tk2;
}

__global__ __launch_bounds__(64, 1) void ttt_run(
    const int* __restrict__ seq, const float* __restrict__ enc,
    const float* __restrict__ Gg,
    const float* __restrict__ w1g, const float* __restrict__ b1g,
    const float* __restrict__ w2g, const float* __restrict__ b2g,
    const float* __restrict__ woutg, const float* __restrict__ boutg,
    float* __restrict__ out) {
  __shared__ float enc_s[VOCAB * HD];     // 16 KB
  __shared__ float G_s[VOCAB * VOCAB];    // 16 KB
  __shared__ int   seq_s[SEQLEN];         // 8 KB
  __shared__ float sd_s[64];
  __shared__ float ctx_s[64];
  const int b = blockIdx.x, l = threadIdx.x;
  const int i = l & 31, half = l >> 5;

  #pragma unroll
  for (int q = 0; q < 16; ++q)
    ((float4*)enc_s)[l + 64 * q] = ((const float4*)enc)[l + 64 * q];
  #pragma unroll
  for (int q = 0; q < 16; ++q)
    ((float4*)G_s)[l + 64 * q] = ((const float4*)Gg)[l + 64 * q];
  const int4* seqg = (const int4*)(seq + b * SEQLEN);
  #pragma unroll
  for (int q = 0; q < 8; ++q)
    ((int4*)seq_s)[l + 64 * q] = seqg[l + 64 * q];

  f2 W1[16], W2T[16];
  float W2R[32];
  #pragma unroll
  for (int q = 0; q < 8; ++q) {
    float4 t = *(const float4*)&w1g[i * 64 + half * 32 + 4 * q];
    W1[2 * q]     = f2{t.x, t.y};
    W1[2 * q + 1] = f2{t.z, t.w};
  }
  #pragma unroll
  for (int q = 0; q < 8; ++q) {
    float4 t = *(const float4*)&w2g[l * 32 + 4 * q];
    W2R[4 * q + 0] = t.x; W2R[4 * q + 1] = t.y;
    W2R[4 * q + 2] = t.z; W2R[4 * q + 3] = t.w;
  }
  #pragma unroll
  for (int r = 0; r < 16; ++r)
    W2T[r] = f2{w2g[(half * 32 + 2 * r) * 32 + i], w2g[(half * 32 + 2 * r + 1) * 32 + i]};
  float b1r = b1g[i];
  float b2r = b2g[l];
  __syncthreads();

  int2 tk  = *(const int2*)&seq_s[0];
  int2 tk1 = *(const int2*)&seq_s[2];
  f2 KA[16], KB[16];
  float vvA, vvB;
  {
    const float* kr = &enc_s[tk.x * HD + half * 32];
    #pragma unroll
    for (int q = 0; q < 8; ++q) {
      float4 t = *(const float4*)&kr[4 * q];
      KA[2 * q]     = f2{t.x, t.y};
      KA[2 * q + 1] = f2{t.z, t.w};
    }
    vvA = enc_s[tk.y * HD + l];
  }
  // POF init: full dot W1 @ k_0 (first step: dhp=0, KKF=0)
  float POF, KKF = 0.f, dhp = 0.f;
  {
    f2 p0 = {0.f, 0.f}, p1 = {0.f, 0.f};
    #pragma unroll
    for (int c = 0; c < 16; c += 2) {
      p0 = __builtin_elementwise_fma(W1[c + 0], KA[c + 0], p0);
      p1 = __builtin_elementwise_fma(W1[c + 1], KA[c + 1], p1);
    }
    f2 ps = p0 + p1;
    float pp = ps.x + ps.y;
    POF = pp + __shfl_xor(pp, 32, 64);
  }

  // 511 unrolled pairs (1022 steps) + 1 final step = 1023
  for (int s = 0; s < NSTEPS - 1; s += 2) {
    ttt_step(l, half, enc_s, G_s, seq_s, sd_s, W1, W2R, W2T, b1r, b2r,
             KA, vvA, KB, vvB, POF, KKF, dhp, tk, tk1, 2 * s + 4);
    ttt_step(l, half, enc_s, G_s, seq_s, sd_s, W1, W2R, W2T, b1r, b2r,
             KB, vvB, KA, vvA, POF, KKF, dhp, tk, tk1, 2 * s + 6);
  }
  ttt_step(l, half, enc_s, G_s, seq_s, sd_s, W1, W2R, W2T, b1r, b2r,
           KA, vvA, KB, vvB, POF, KKF, dhp, tk, tk1, 2046 /*result unused*/);

  // ---- tail: ctx = w2f @ relu(w1f @ enc[seq[L-1]] + b1f) + b2f ----
  {
    int tok = seq_s[SEQLEN - 1];
    f2 K[16];
    const float* kr = &enc_s[tok * HD + half * 32];
    #pragma unroll
    for (int q = 0; q < 8; ++q) {
      float4 t = *(const float4*)&kr[4 * q];
      K[2 * q]     = f2{t.x, t.y};
      K[2 * q + 1] = f2{t.z, t.w};
    }
    f2 a0 = {0.f, 0.f}, a1 = {0.f, 0.f};
    #pragma unroll
    for (int c = 0; c < 16; c += 2) {
      a0 = __builtin_elementwise_fma(W1[c + 0], K[c + 0], a0);
      a1 = __builtin_elementwise_fma(W1[c + 1], K[c + 1], a1);
    }
    f2 as = a0 + a1;
    float part = as.x + as.y;
    float pre = part + __shfl_xor(part, 32, 64) + b1r;
    float h = fmaxf(pre, 0.f);
    float sh[32];
    #pragma unroll
    for (int c = 0; c < 32; ++c)
      sh[c] = __int_as_float(__builtin_amdgcn_readlane(__float_as_int(h), c));
    float q0 = b2r, q1 = 0.f, q2 = 0.f, q3 = 0.f;
    #pragma unroll
    for (int c = 0; c < 32; c += 4) {
      q0 = fmaf(W2R[c + 0], sh[c + 0], q0);
      q1 = fmaf(W2R[c + 1], sh[c + 1], q1);
      q2 = fmaf(W2R[c + 2], sh[c + 2], q2);
      q3 = fmaf(W2R[c + 3], sh[c + 3], q3);
    }
    ctx_s[l] = (q0 + q1) + (q2 + q3);
    __syncthreads();
    float acc = boutg[l];
    #pragma unroll 8
    for (int jj = 0; jj < 64; ++jj) acc = fmaf(woutg[l * 64 + jj], ctx_s[jj], acc);
    out[b * 64 + l] = acc;
  }
}

extern "C" void kernel_launch(void* const* d_in, const int* in_sizes, int n_in,
                              void* d_out, int out_size, void* d_ws, size_t ws_size,
                              hipStream_t stream) {
  const int*   seq   = (const int*)d_in[0];
  const float* embed = (const float*)d_in[1];
  const float* ffw1  = (const float*)d_in[2];
  const float* ffb1  = (const float*)d_in[3];
  const float* ffw2  = (const float*)d_in[4];
  const float* ffb2  = (const float*)d_in[5];
  const float* ln_g  = (const float*)d_in[6];
  const float* ln_b  = (const float*)d_in[7];
  const float* w1    = (const float*)d_in[8];
  const float* b1    = (const float*)d_in[9];
  const float* w2    = (const float*)d_in[10];
  const float* b2    = (const float*)d_in[11];
  const float* wout  = (const float*)d_in[12];
  const float* bout  = (const float*)d_in[13];
  float* enc = (float*)d_ws;           // 4096 floats
  float* G   = (float*)d_ws + 4096;    // 4096 floats

  enc_build<<<VOCAB, 64, 0, stream>>>(embed, ffw1, ffb1, ffw2, ffb2, ln_g, ln_b, enc);
  gram_build<<<VOCAB, 64, 0, stream>>>(enc, G);
  ttt_run<<<BATCH, 64, 0, stream>>>(seq, enc, G, w1, b1, w2, b2, wout, bout, (float*)d_out);
}